// Round 6
// baseline (167.942 us; speedup 1.0000x reference)
//
#include <hip/hip_runtime.h>
#include <hip/hip_bf16.h>
#include <math.h>

// ROI Align, fused taps form. B=2, K=128, C=256, IMG=512, OH=OW=16.
// Inputs (fp32 unless noted): bboxess[B,K,4], counts[B,1] (i32),
// p2[B,C,128,128], p3[B,C,64,64], p4[B,C,32,32], p5[B,C,16,16], p6 (unused),
// img_h, img_w (scalars, always 512 -> hardcoded).
// Output: FLOAT32 [B,K,C,16,16] (reference returns f32; harness reads f32).

constexpr int Bn = 2, Kn = 128, Cn = 256;
constexpr int CSPLIT = 4;            // channel-split blocks per box
constexpr int CCH = Cn / CSPLIT;     // 64 channels per block

__device__ __forceinline__ void to_level(int F, int psize,
                                         int& g0i, int& g1i, float& v) {
  // stage 1: full-res pixel -> pair of level-map pixels
  // (f+0.5)*psize/512 is exact in f32 for psize in {16,32,64,128}, F<=511.
  float g = fmaxf(((float)F + 0.5f) * (float)psize * (1.0f / 512.0f) - 0.5f, 0.0f);
  float g0 = floorf(g);
  v = g - g0;
  g0i = (int)g0;
  g1i = min(g0i + 1, psize - 1);
}

__device__ __forceinline__ void taps1(int o, int start, int croplen, int psize,
                                      int idx[4], float wt[4]) {
  // stage 2: output bin -> pair of full-res pixels (torch resize rule)
  float s = fmaxf(((float)o + 0.5f) * (float)croplen * (1.0f / 16.0f) - 0.5f, 0.0f);
  float f0 = floorf(s);
  float w1 = s - f0;
  int f0i = (int)f0;
  int f1i = min(f0i + 1, croplen - 1);
  int a0, a1, b0, b1;
  float va, vb;
  to_level(start + f0i, psize, a0, a1, va);
  to_level(start + f1i, psize, b0, b1, vb);
  idx[0] = a0; idx[1] = a1; idx[2] = b0; idx[3] = b1;
  wt[0] = (1.0f - w1) * (1.0f - va);
  wt[1] = (1.0f - w1) * va;
  wt[2] = w1 * (1.0f - vb);
  wt[3] = w1 * vb;
}

__global__ __launch_bounds__(256, 4)
void roialign_kernel(const float* __restrict__ bbox,
                     const int* __restrict__ counts,
                     const float* __restrict__ p2,
                     const float* __restrict__ p3,
                     const float* __restrict__ p4,
                     const float* __restrict__ p5,
                     float* __restrict__ out) {
  const int blk = blockIdx.x;
  const int cpart = blk & (CSPLIT - 1);
  const int box = blk / CSPLIT;              // 0..255 = b*Kn + k
  const int b = box / Kn;
  const int k = box - b * Kn;
  const int t = threadIdx.x;                 // 0..255 = oy*16 + ox
  const int oy = t >> 4, ox = t & 15;

  const long outBase = ((long)box * Cn + cpart * CCH) * 256 + t;

  const bool valid = (k < counts[b]);
  if (!valid) {
    for (int c = 0; c < CCH; ++c) out[outBase + (long)c * 256] = 0.0f;
    return;
  }

  // ---- per-box parameters ----
  const float y1f = bbox[box * 4 + 0], x1f = bbox[box * 4 + 1];
  const float y2f = bbox[box * 4 + 2], x2f = bbox[box * 4 + 3];
  const float area = (y2f - y1f) * (x2f - x1f);  // f32, matches jnp bit-exact
  // lvl-2 = clip(round(0.5*log2(area)-3),2,5)-2, via exact area thresholds.
  // round is half-even: t=2.5->2 (so strict >2048), t=3.5->4 (so >=8192),
  // t=4.5->4 (so strict >32768).
  const int lvl = (area > 2048.0f) + (area >= 8192.0f) + (area > 32768.0f);
  const int ph = 128 >> lvl;                 // 128,64,32,16 (square)
  const int pw = ph;

  // round-half-even to match jnp.round
  const int bi0 = (int)rintf(y1f), bi1 = (int)rintf(x1f);
  const int bi2 = (int)rintf(y2f), bi3 = (int)rintf(x2f);
  const int y1 = min(max(bi0, 0), 511);
  const int x1 = min(max(bi1, 0), 511);
  const int y2 = min(max(bi2, y1 + 1), 512);
  const int x2 = min(max(bi3, x1 + 1), 512);

  int iy[4], ix[4];
  float wy[4], wx[4];
  taps1(oy, y1, y2 - y1, ph, iy, wy);
  taps1(ox, x1, x2 - x1, pw, ix, wx);

  int off[16];
  float wgt[16];
#pragma unroll
  for (int a = 0; a < 4; ++a)
#pragma unroll
    for (int bb = 0; bb < 4; ++bb) {
      off[a * 4 + bb] = iy[a] * pw + ix[bb];
      wgt[a * 4 + bb] = wy[a] * wx[bb];
    }

  const float* Pbase;
  switch (lvl) {
    case 0: Pbase = p2; break;
    case 1: Pbase = p3; break;
    case 2: Pbase = p4; break;
    default: Pbase = p5; break;
  }
  const int planeStride = ph * pw;
  const float* plane = Pbase + ((long)b * Cn + cpart * CCH) * planeStride;

#pragma unroll 2
  for (int c = 0; c < CCH; ++c) {
    const float* __restrict__ P = plane + (long)c * planeStride;
    float acc = 0.0f;
#pragma unroll
    for (int i = 0; i < 16; ++i) acc = fmaf(wgt[i], P[off[i]], acc);
    out[outBase + (long)c * 256] = acc;
  }
}

extern "C" void kernel_launch(void* const* d_in, const int* in_sizes, int n_in,
                              void* d_out, int out_size, void* d_ws, size_t ws_size,
                              hipStream_t stream) {
  const float* bbox = (const float*)d_in[0];
  const int* counts = (const int*)d_in[1];
  const float* p2 = (const float*)d_in[2];
  const float* p3 = (const float*)d_in[3];
  const float* p4 = (const float*)d_in[4];
  const float* p5 = (const float*)d_in[5];
  float* out = (float*)d_out;

  dim3 grid(Bn * Kn * CSPLIT);
  dim3 block(256);
  roialign_kernel<<<grid, block, 0, stream>>>(bbox, counts, p2, p3, p4, p5, out);
}

// Round 7
// 164.687 us; speedup vs baseline: 1.0198x; 1.0198x over previous
//
#include <hip/hip_runtime.h>
#include <math.h>

// ROI Align, fused taps form. B=2, K=128, C=256, IMG=512, OH=OW=16.
// Inputs: bboxess[B,K,4] f32, counts[B,1] i32, p2..p5 f32 pyramids, p6 unused.
// Output: f32 [B,K,C,16,16].
// R6 counters: 77us, VALUBusy 9.7%, Occ 17%, HBM 13% -> latency/occupancy-bound.
// R7: CSPLIT 4->8 (2048 blocks, 8/CU), launch_bounds(256,8) (VGPR was exactly
// 64 naturally), x-taps paired into 8B gathers (16 -> 8 loads/channel, exact).

constexpr int Bn = 2, Kn = 128, Cn = 256;
constexpr int CSPLIT = 8;            // channel-split blocks per box
constexpr int CCH = Cn / CSPLIT;     // 32 channels per block

// stage 1 (y): full-res pixel -> two level rows + weights
__device__ __forceinline__ void to_level(int F, int psize,
                                         int& g0i, int& g1i, float& v) {
  float g = fmaxf(((float)F + 0.5f) * (float)psize * (1.0f / 512.0f) - 0.5f, 0.0f);
  float g0 = floorf(g);
  v = g - g0;
  g0i = (int)g0;
  g1i = min(g0i + 1, psize - 1);
}

// stage 1 (x): full-res pixel -> ADJACENT level pair [base, base+1] + weights.
// When g0==psize-1 the reference puts all weight on g0 (g1 clamps to g0);
// we shift base to psize-2 and use weights (0,1): bit-equivalent, in-bounds.
__device__ __forceinline__ void to_level_pair(int F, int psize,
                                              int& base, float& wlo, float& whi) {
  float g = fmaxf(((float)F + 0.5f) * (float)psize * (1.0f / 512.0f) - 0.5f, 0.0f);
  float g0 = floorf(g);
  float v = g - g0;
  int g0i = (int)g0;
  if (g0i >= psize - 1) { base = psize - 2; wlo = 0.0f; whi = 1.0f; }
  else                  { base = g0i;       wlo = 1.0f - v; whi = v; }
}

__device__ __forceinline__ float2 load_f2(const float* p) {
  float2 v;                       // alignment-4 honest load; compiler may fuse
  __builtin_memcpy(&v, p, 8);    // to global_load_dwordx2, else 2x dword
  return v;
}

__global__ __launch_bounds__(256, 8)
void roialign_kernel(const float* __restrict__ bbox,
                     const int* __restrict__ counts,
                     const float* __restrict__ p2,
                     const float* __restrict__ p3,
                     const float* __restrict__ p4,
                     const float* __restrict__ p5,
                     float* __restrict__ out) {
  const int blk = blockIdx.x;
  const int cpart = blk & (CSPLIT - 1);
  const int box = blk / CSPLIT;              // 0..255 = b*Kn + k
  const int b = box >> 7;                    // /128
  const int k = box & 127;
  const int t = threadIdx.x;                 // 0..255 = oy*16 + ox
  const int oy = t >> 4, ox = t & 15;

  const long outBase = ((long)box * Cn + cpart * CCH) * 256 + t;

  if (k >= counts[b]) {
    for (int c = 0; c < CCH; ++c) out[outBase + (long)c * 256] = 0.0f;
    return;
  }

  // ---- per-box parameters ----
  const float y1f = bbox[box * 4 + 0], x1f = bbox[box * 4 + 1];
  const float y2f = bbox[box * 4 + 2], x2f = bbox[box * 4 + 3];
  const float area = (y2f - y1f) * (x2f - x1f);
  // lvl = clip(round(0.5*log2(area)-3),2,5)-2 via exact half-even thresholds
  const int lvl = (area > 2048.0f) + (area >= 8192.0f) + (area > 32768.0f);
  const int ph = 128 >> lvl;                 // 128,64,32,16 (square)
  const int pw = ph;

  const int y1 = min(max((int)rintf(y1f), 0), 511);
  const int x1 = min(max((int)rintf(x1f), 0), 511);
  const int y2 = min(max((int)rintf(y2f), y1 + 1), 512);
  const int x2 = min(max((int)rintf(x2f), x1 + 1), 512);

  // ---- y taps: 4 (row, weight) ----
  int iyr[4];
  float wyr[4];
  {
    const int crop = y2 - y1;
    float s = fmaxf(((float)oy + 0.5f) * (float)crop * (1.0f / 16.0f) - 0.5f, 0.0f);
    float f0 = floorf(s);
    float w1 = s - f0;
    int f0i = (int)f0;
    int f1i = min(f0i + 1, crop - 1);
    int a0, a1, b0, b1; float va, vb;
    to_level(y1 + f0i, ph, a0, a1, va);
    to_level(y1 + f1i, ph, b0, b1, vb);
    iyr[0] = a0; iyr[1] = a1; iyr[2] = b0; iyr[3] = b1;
    wyr[0] = (1.0f - w1) * (1.0f - va);
    wyr[1] = (1.0f - w1) * va;
    wyr[2] = w1 * (1.0f - vb);
    wyr[3] = w1 * vb;
  }

  // ---- x taps: 2 adjacent pairs ----
  int bx[2];
  float wxl[2], wxh[2];
  {
    const int crop = x2 - x1;
    float s = fmaxf(((float)ox + 0.5f) * (float)crop * (1.0f / 16.0f) - 0.5f, 0.0f);
    float f0 = floorf(s);
    float w1 = s - f0;
    int f0i = (int)f0;
    int f1i = min(f0i + 1, crop - 1);
    float l0, h0, l1, h1;
    to_level_pair(x1 + f0i, pw, bx[0], l0, h0);
    to_level_pair(x1 + f1i, pw, bx[1], l1, h1);
    wxl[0] = (1.0f - w1) * l0; wxh[0] = (1.0f - w1) * h0;
    wxl[1] = w1 * l1;          wxh[1] = w1 * h1;
  }

  // ---- 8 pair-offsets + 16 weights (ref accumulation order: a-major) ----
  int off[8];
  float wl[8], wh[8];
#pragma unroll
  for (int r = 0; r < 4; ++r)
#pragma unroll
    for (int p = 0; p < 2; ++p) {
      off[r * 2 + p] = iyr[r] * pw + bx[p];
      wl[r * 2 + p] = wyr[r] * wxl[p];
      wh[r * 2 + p] = wyr[r] * wxh[p];
    }

  const float* Pbase;
  switch (lvl) {
    case 0: Pbase = p2; break;
    case 1: Pbase = p3; break;
    case 2: Pbase = p4; break;
    default: Pbase = p5; break;
  }
  const int planeStride = ph * pw;
  const float* plane = Pbase + ((long)b * Cn + cpart * CCH) * planeStride;

  for (int c = 0; c < CCH; ++c) {
    const float* __restrict__ P = plane + (long)c * planeStride;
    float acc = 0.0f;
#pragma unroll
    for (int i = 0; i < 8; ++i) {
      const float2 v = load_f2(P + off[i]);
      acc = fmaf(wl[i], v.x, acc);
      acc = fmaf(wh[i], v.y, acc);
    }
    out[outBase + (long)c * 256] = acc;
  }
}

extern "C" void kernel_launch(void* const* d_in, const int* in_sizes, int n_in,
                              void* d_out, int out_size, void* d_ws, size_t ws_size,
                              hipStream_t stream) {
  const float* bbox = (const float*)d_in[0];
  const int* counts = (const int*)d_in[1];
  const float* p2 = (const float*)d_in[2];
  const float* p3 = (const float*)d_in[3];
  const float* p4 = (const float*)d_in[4];
  const float* p5 = (const float*)d_in[5];
  float* out = (float*)d_out;

  dim3 grid(Bn * Kn * CSPLIT);
  dim3 block(256);
  roialign_kernel<<<grid, block, 0, stream>>>(bbox, counts, p2, p3, p4, p5, out);
}

// Round 8
// 123.801 us; speedup vs baseline: 1.3566x; 1.3303x over previous
//
#include <hip/hip_runtime.h>
#include <math.h>

// ROI Align, fused taps form. B=2, K=128, C=256, IMG=512, OH=OW=16.
// Inputs: bboxess[B,K,4] f32, counts[B,1] i32, p2..p5 f32 pyramids, p6 unused.
// Output: f32 [B,K,C,16,16].
// R6: 77us, Occ 17%, VALU 9.7% -> latency-bound. R7: Occ 49% but 70us ->
// occupancy didn't help => scattered-gather tag-pipe bound (~1 line/cy/CU).
// R8: stage the touched level-region (provably <=235 px/channel for this
// input distribution; p5/p6 unreachable) in LDS once per block; interpolate
// from LDS via ds_read2. Gathers leave the L1 path entirely.

constexpr int Bn = 2, Kn = 128, Cn = 256;
constexpr int CSPLIT = 8;            // channel-split blocks per box
constexpr int CCH = Cn / CSPLIT;     // 32 channels per block
constexpr int MAXPX = 240;           // >= max ey*ex_pad (bound analysis in R8 notes)

__device__ __forceinline__ float levelg(int F, int psize) {
  // full-res pixel -> continuous level coord (exact in f32 for these sizes)
  return fmaxf(((float)F + 0.5f) * (float)psize * (1.0f / 512.0f) - 0.5f, 0.0f);
}

__device__ __forceinline__ void to_level(int F, int psize,
                                         int& g0i, int& g1i, float& v) {
  float g = levelg(F, psize);
  float g0 = floorf(g);
  v = g - g0;
  g0i = (int)g0;
  g1i = min(g0i + 1, psize - 1);
}

// x variant: adjacent pair [base, base+1]; edge clamp shifts base to psize-2
// with weights (0,1) -> bit-equivalent to ref's duplicated-tap form.
__device__ __forceinline__ void to_level_pair(int F, int psize,
                                              int& base, float& wlo, float& whi) {
  float g = levelg(F, psize);
  float g0 = floorf(g);
  float v = g - g0;
  int g0i = (int)g0;
  if (g0i >= psize - 1) { base = psize - 2; wlo = 0.0f; whi = 1.0f; }
  else                  { base = g0i;       wlo = 1.0f - v; whi = v; }
}

__device__ __forceinline__ int pair_base(int F, int psize) {
  return min((int)floorf(levelg(F, psize)), psize - 2);
}

__device__ __forceinline__ void bin_f(int o, int crop,
                                      int& f0i, int& f1i, float& w1) {
  float s = fmaxf(((float)o + 0.5f) * (float)crop * (1.0f / 16.0f) - 0.5f, 0.0f);
  float f0 = floorf(s);
  w1 = s - f0;
  f0i = (int)f0;
  f1i = min(f0i + 1, crop - 1);
}

__device__ __forceinline__ float2 load_f2(const float* p) {
  float2 v;
  __builtin_memcpy(&v, p, 8);
  return v;
}

__global__ __launch_bounds__(256, 5)
void roialign_kernel(const float* __restrict__ bbox,
                     const int* __restrict__ counts,
                     const float* __restrict__ p2,
                     const float* __restrict__ p3,
                     const float* __restrict__ p4,
                     const float* __restrict__ p5,
                     float* __restrict__ out) {
  __shared__ float smem[CCH * MAXPX];          // 30.7 KB -> 5 blocks/CU

  const int blk = blockIdx.x;
  const int cpart = blk & (CSPLIT - 1);
  const int box = blk / CSPLIT;                // 0..255 = b*Kn + k
  const int b = box >> 7;
  const int k = box & 127;
  const int t = threadIdx.x;                   // 0..255 = oy*16 + ox
  const int oy = t >> 4, ox = t & 15;

  const long outBase = ((long)box * Cn + cpart * CCH) * 256 + t;

  if (k >= counts[b]) {                        // block-uniform branch
    for (int c = 0; c < CCH; ++c) out[outBase + (long)c * 256] = 0.0f;
    return;
  }

  // ---- per-box parameters ----
  const float y1f = bbox[box * 4 + 0], x1f = bbox[box * 4 + 1];
  const float y2f = bbox[box * 4 + 2], x2f = bbox[box * 4 + 3];
  const float area = (y2f - y1f) * (x2f - x1f);
  // lvl = clip(round(0.5*log2(area)-3),2,5)-2 via exact half-even thresholds
  const int lvl = (area > 2048.0f) + (area >= 8192.0f) + (area > 32768.0f);
  const int ph = 128 >> lvl;                   // plane is square
  const int pw = ph;

  const int y1 = min(max((int)rintf(y1f), 0), 511);
  const int x1 = min(max((int)rintf(x1f), 0), 511);
  const int y2 = min(max((int)rintf(y2f), y1 + 1), 512);
  const int x2 = min(max((int)rintf(x2f), x1 + 1), 512);
  const int cropy = y2 - y1, cropx = x2 - x1;

  // ---- this thread's y taps: 4 (row, weight) ----
  int iyr[4];
  float wyr[4];
  {
    int f0i, f1i; float w1;
    bin_f(oy, cropy, f0i, f1i, w1);
    int a0, a1, b0, b1; float va, vb;
    to_level(y1 + f0i, ph, a0, a1, va);
    to_level(y1 + f1i, ph, b0, b1, vb);
    iyr[0] = a0; iyr[1] = a1; iyr[2] = b0; iyr[3] = b1;
    wyr[0] = (1.0f - w1) * (1.0f - va);
    wyr[1] = (1.0f - w1) * va;
    wyr[2] = w1 * (1.0f - vb);
    wyr[3] = w1 * vb;
  }

  // ---- this thread's x taps: 2 adjacent pairs ----
  int bx[2];
  float wxl[2], wxh[2];
  {
    int f0i, f1i; float w1;
    bin_f(ox, cropx, f0i, f1i, w1);
    float l0, h0, l1, h1;
    to_level_pair(x1 + f0i, pw, bx[0], l0, h0);
    to_level_pair(x1 + f1i, pw, bx[1], l1, h1);
    wxl[0] = (1.0f - w1) * l0; wxh[0] = (1.0f - w1) * h0;
    wxl[1] = w1 * l1;          wxh[1] = w1 * h1;
  }

  // ---- block-uniform touched region (taps are monotone in oy/ox) ----
  int y_lo, y_hi, x_lo, x_hi;
  {
    int f0a, f1a, f0b, f1b; float wd;
    bin_f(0, cropy, f0a, f1a, wd);
    bin_f(15, cropy, f0b, f1b, wd);
    int g0, g1; float vd;
    to_level(y1 + f0a, ph, g0, g1, vd); y_lo = g0;
    to_level(y1 + f1b, ph, g0, g1, vd); y_hi = g1;
    bin_f(0, cropx, f0a, f1a, wd);
    bin_f(15, cropx, f0b, f1b, wd);
    x_lo = pair_base(x1 + f0a, pw);
    x_hi = pair_base(x1 + f1b, pw) + 1;
  }
  const int ey = y_hi - y_lo + 1;
  const int ex = x_hi - x_lo + 1;              // >= 2
  const int ex_pad = ex | 1;                   // odd stride -> bank spread
  const int region = ey * ex;

  const float* Pbase;
  switch (lvl) {
    case 0: Pbase = p2; break;
    case 1: Pbase = p3; break;
    case 2: Pbase = p4; break;
    default: Pbase = p5; break;                // unreachable for this dist
  }
  const int planeStride = ph * pw;
  const float* plane = Pbase + ((long)b * Cn + cpart * CCH) * planeStride;

  if (ey * ex_pad > MAXPX) {
    // Safety fallback (unreachable by bound analysis): direct global gathers.
    int off[8];
    float wl[8], wh[8];
#pragma unroll
    for (int r = 0; r < 4; ++r)
#pragma unroll
      for (int p = 0; p < 2; ++p) {
        off[r * 2 + p] = iyr[r] * pw + bx[p];
        wl[r * 2 + p] = wyr[r] * wxl[p];
        wh[r * 2 + p] = wyr[r] * wxh[p];
      }
    for (int c = 0; c < CCH; ++c) {
      const float* __restrict__ P = plane + (long)c * planeStride;
      float acc = 0.0f;
#pragma unroll
      for (int i = 0; i < 8; ++i) {
        const float2 v = load_f2(P + off[i]);
        acc = fmaf(wl[i], v.x, acc);
        acc = fmaf(wh[i], v.y, acc);
      }
      out[outBase + (long)c * 256] = acc;
    }
    return;
  }

  // ---- stage region: one element per thread per channel (region<=235<256) --
  {
    const bool act = (t < region);
    int sr = 0, sx = 0;
    if (act) { sr = t / ex; sx = t - sr * ex; }
    const int gsrc = (y_lo + sr) * pw + (x_lo + sx);
    const int ldst = sr * ex_pad + sx;
    if (act) {
#pragma unroll 4
      for (int c = 0; c < CCH; ++c)
        smem[c * MAXPX + ldst] = plane[(long)c * planeStride + gsrc];
    }
  }
  __syncthreads();

  // ---- LDS word-offsets for this thread's 8 tap-pairs ----
  int loff[8];
  float wl[8], wh[8];
#pragma unroll
  for (int r = 0; r < 4; ++r)
#pragma unroll
    for (int p = 0; p < 2; ++p) {
      loff[r * 2 + p] = (iyr[r] - y_lo) * ex_pad + (bx[p] - x_lo);
      wl[r * 2 + p] = wyr[r] * wxl[p];
      wh[r * 2 + p] = wyr[r] * wxh[p];
    }

  // ---- interpolate from LDS (same FP order as R6/R7: r-major, lo then hi) --
  for (int c = 0; c < CCH; ++c) {
    const float* __restrict__ base = smem + c * MAXPX;
    float acc = 0.0f;
#pragma unroll
    for (int i = 0; i < 8; ++i) {
      acc = fmaf(wl[i], base[loff[i]], acc);       // ds_read2_b32 pair
      acc = fmaf(wh[i], base[loff[i] + 1], acc);
    }
    out[outBase + (long)c * 256] = acc;
  }
}

extern "C" void kernel_launch(void* const* d_in, const int* in_sizes, int n_in,
                              void* d_out, int out_size, void* d_ws, size_t ws_size,
                              hipStream_t stream) {
  const float* bbox = (const float*)d_in[0];
  const int* counts = (const int*)d_in[1];
  const float* p2 = (const float*)d_in[2];
  const float* p3 = (const float*)d_in[3];
  const float* p4 = (const float*)d_in[4];
  const float* p5 = (const float*)d_in[5];
  float* out = (float*)d_out;

  dim3 grid(Bn * Kn * CSPLIT);
  dim3 block(256);
  roialign_kernel<<<grid, block, 0, stream>>>(bbox, counts, p2, p3, p4, p5, out);
}